// Round 2
// baseline (341.131 us; speedup 1.0000x reference)
//
#include <hip/hip_runtime.h>

// Problem constants (fixed by setup_inputs)
constexpr int B = 4;
constexpr int N = 768;
constexpr int D = 16;           // per-node embedding dim
constexpr int E = 12288;        // edges per batch
constexpr int NN = N * N;      // 589824 pairs per batch
constexpr int PAIRS = B * NN;  // 2,359,296
constexpr long long EE_FLOATS = (long long)PAIRS * 2 * D;  // 75,497,472
constexpr int RPB = 4;          // rows per block
constexpr int NQ = N * 4;       // float4s per batch of embeddings (3072 = 48 KB)

__device__ __forceinline__ float dot4(float4 a, float4 b) {
    return a.x * b.x + a.y * b.y + a.z * b.z + a.w * b.w;
}
__device__ __forceinline__ float absdiff4(float4 a, float4 b) {
    return fabsf(a.x - b.x) + fabsf(a.y - b.y) + fabsf(a.z - b.z) + fabsf(a.w - b.w);
}
// lane-varying 4-way select (c is per-lane constant -> 3 cndmask chains)
__device__ __forceinline__ float4 sel4(int c, float4 a0, float4 a1, float4 a2, float4 a3) {
    float4 r = a0;
    if (c == 1) r = a1;
    if (c == 2) r = a2;
    if (c == 3) r = a3;
    return r;
}

// Fused EE fill + logits + truth-zero. One block per 4 consecutive (b,i) rows.
//
// Key structural property: the main loop has NO global loads. Batch b's
// embeddings (48 KB) are staged in LDS once; the 24-iteration store loop is
// ds_read_b128 (lgkmcnt) -> global_store_dwordx4 (vmcnt, never waited on).
// Global loads share the vmcnt queue with stores -- the old kernel's
// load->store dependency drained the store queue every iteration, capping it
// at ~2.8 TB/s; a pure store stream reaches ~6 TB/s (fillBuffer evidence).
//
// float4 index f = t + k*256 within a row's 6144; pair j = f>>3, quarter
// q = f&7 (loop-invariant since 256 % 8 == 0):
//   q<4  lanes store e_i quarter q; q>=4 lanes store e_j quarter q-4.
// Logits are fused: the 4 lanes holding e_j's quarters butterfly-reduce
// (shfl_xor 1,2 -> DPP, stays in the VALU pipe) dot(e_j,W2) and sum|e_i-e_j|;
// lane q==4 writes logits[j] and truth[j]=0.
__global__ __launch_bounds__(256) void rowgroup_fused_kernel(
    const float4* __restrict__ emb4, const float* __restrict__ W,
    const float* __restrict__ bias, float4* __restrict__ ee4,
    float* __restrict__ logits, float* __restrict__ truth) {
    __shared__ float4 semb[NQ];  // 48 KB: [node][quarter]

    const int g = blockIdx.x;                    // 0 .. B*N/RPB-1 (=767)
    const int b = g / (N / RPB);
    const int i0 = (g - b * (N / RPB)) * RPB;
    const float4* __restrict__ eb = emb4 + (size_t)b * NQ;

    const int t = threadIdx.x;
#pragma unroll
    for (int k = 0; k < NQ / 256; ++k)           // 12 coalesced iters
        semb[t + k * 256] = eb[t + k * 256];
    __syncthreads();

    const int q = t & 7;
    const int qq = q & 3;
    const bool isI = (q < 4);
    const int jn0 = t >> 3;                      // pair offset within k-step (0..31)
    const bool isWriter = (q == 4);

    const float4* __restrict__ W4 = (const float4*)W;  // 8 float4 = 32 weights
    const float4 wa0 = W4[0], wa1 = W4[1], wa2 = W4[2], wa3 = W4[3];
    const float4 myWb = sel4(qq, W4[4], W4[5], W4[6], W4[7]);
    const float bb = bias[0];

#pragma unroll 1
    for (int r = 0; r < RPB; ++r) {
        const int i = i0 + r;
        const int row = b * N + i;
        const float4 e0 = semb[i * 4 + 0], e1 = semb[i * 4 + 1];
        const float4 e2 = semb[i * 4 + 2], e3 = semb[i * 4 + 3];
        const float base =
            dot4(e0, wa0) + dot4(e1, wa1) + dot4(e2, wa2) + dot4(e3, wa3) + bb;
        const float4 myEi = sel4(qq, e0, e1, e2, e3);

        float4* __restrict__ orow = ee4 + (size_t)row * (N * 8);
        float* __restrict__ lrow = logits + (size_t)row * N;
        float* __restrict__ trow = truth + (size_t)row * N;
#pragma unroll
        for (int k = 0; k < (N * 8) / 256; ++k) {  // 24 iterations
            const int f = t + k * 256;
            const int j = jn0 + k * 32;
            const int node = isI ? i : j;
            const float4 v = semb[node * 4 + qq];  // LDS only -- no vmcnt
            orow[f] = v;                           // fire-and-forget store

            // fused logit for pair j (meaningful in each aligned 4-lane
            // group q=4..7 holding e_j quarters 0..3)
            float pa = dot4(v, myWb);
            float pd = absdiff4(myEi, v);
            pa += __shfl_xor(pa, 1, 64);
            pd += __shfl_xor(pd, 1, 64);
            pa += __shfl_xor(pa, 2, 64);
            pd += __shfl_xor(pd, 2, 64);
            if (isWriter) {
                lrow[j] = (pd != 0.f) ? (base + pa) : -10.0f;
                trow[j] = 0.0f;
            }
        }
    }
}

// Edge scatter into truth. Duplicates idempotent (plain store of 1.0).
// Runs after the fused kernel's zeroing (same stream => ordered).
__global__ void truth_scatter_kernel(const int* __restrict__ edges,
                                     float* __restrict__ truth) {
    int tid = blockIdx.x * blockDim.x + threadIdx.x;
    if (tid >= B * E) return;
    int b = tid / E;
    int e = tid - b * E;
    int src = edges[b * 2 * E + e];
    int dst = edges[b * 2 * E + E + e];
    truth[(size_t)b * NN + src * N + dst] = 1.0f;
}

extern "C" void kernel_launch(void* const* d_in, const int* in_sizes, int n_in,
                              void* d_out, int out_size, void* d_ws, size_t ws_size,
                              hipStream_t stream) {
    const float4* emb4 = (const float4*)d_in[0];  // [B,N,D] fp32 -> 4 float4/node
    const int* edges = (const int*)d_in[1];       // [B,2,E]
    const float* W = (const float*)d_in[2];       // [2D]
    const float* bias = (const float*)d_in[3];    // [1]

    float* out = (float*)d_out;
    float* ee = out;
    float* logits = out + EE_FLOATS;
    float* truth = out + EE_FLOATS + (long long)PAIRS;

    // 768 blocks = exactly 3 blocks/CU (48 KB LDS -> 3 blocks/CU fits 160 KB)
    rowgroup_fused_kernel<<<B * N / RPB, 256, 0, stream>>>(
        emb4, W, bias, (float4*)ee, logits, truth);
    truth_scatter_kernel<<<(B * E + 255) / 256, 256, 0, stream>>>(edges, truth);
}